// Round 8
// baseline (550.473 us; speedup 1.0000x reference)
//
#include <hip/hip_runtime.h>
#include <hip/hip_bf16.h>

#define N_NODES   50000
#define N_PAD     50048                 // ceil64
#define N_EDGES   800000
#define N_REL     16
#define N_GRAPHS  64
#define DIM       128
#define FC_DIM    256
#define N_CLASSES 16

#define NPASS     3                     // rels {0-5},{6-11},{12-16(incl self)}
#define NBINS_P   150528                // 3*N_PAD=150144 pad to 147*1024
#define NBLK_SCAN 147
#define NBLK_B    782                   // N_PAD/64
#define POOL_CH   64
#define GRP_A     6

// ---- ws layout (bytes) ----
#define WS_HIST   0                     // 150528*4 = 602112 } contiguous
#define WS_HG     602112                // 32768             } memset
#define WS_CNT    634880                // 256               } region
#define MEMSET_SZ 635136
#define WS_OFFS   635136                // (150528+1)*4 -> 602368
#define WS_CUR    1237504               // 602112
#define WS_PART   1839616               // 1024
#define WS_SRCS   1840640               // 800000*4 = 3200000
#define WS_X1     5040640               // 50048*128*2 = 12812288
#define WS_X2     17852928              // 12812288
#define WS_AGG    30665216              // bf16 agg: 12812288
#define WS_WB     43477504              // 2*17*128*128*2 = 1114112
#define WS_T      44591616              // 6 slots * 12812288 = 76873728 -> 121.5 MB
#define SLOT_ELEM (N_PAD * DIM)

typedef __attribute__((ext_vector_type(8))) short bf16x8;
typedef __attribute__((ext_vector_type(4))) float f32x4;

__device__ __forceinline__ void atomAddF(float* p, float v) {
#if defined(__gfx90a__) || defined(__gfx942__) || defined(__gfx950__)
    unsafeAtomicAdd(p, v);
#else
    atomicAdd(p, v);
#endif
}

__device__ __forceinline__ float bf2f(unsigned int u) {
    union { float f; unsigned int i; } x; x.i = u << 16; return x.f;
}
__device__ __forceinline__ unsigned short f2bf(float f) {
    union { float f; unsigned int u; } x; x.f = f;
    unsigned int r = x.u + 0x7fff + ((x.u >> 16) & 1);
    return (unsigned short)(r >> 16);
}
__device__ __forceinline__ void accum8(float* qa, uint4 u) {
    qa[0] += bf2f(u.x & 0xffff); qa[1] += bf2f(u.x >> 16);
    qa[2] += bf2f(u.y & 0xffff); qa[3] += bf2f(u.y >> 16);
    qa[4] += bf2f(u.z & 0xffff); qa[5] += bf2f(u.z >> 16);
    qa[6] += bf2f(u.w & 0xffff); qa[7] += bf2f(u.w >> 16);
}
__device__ __forceinline__ void pack16(const float* qa, unsigned short* dst) {
    #pragma unroll
    for (int j = 0; j < 2; ++j) {
        uint4 w;
        w.x = ((unsigned int)f2bf(qa[j*8+1]) << 16) | f2bf(qa[j*8+0]);
        w.y = ((unsigned int)f2bf(qa[j*8+3]) << 16) | f2bf(qa[j*8+2]);
        w.z = ((unsigned int)f2bf(qa[j*8+5]) << 16) | f2bf(qa[j*8+4]);
        w.w = ((unsigned int)f2bf(qa[j*8+7]) << 16) | f2bf(qa[j*8+6]);
        ((uint4*)dst)[j] = w;
    }
}
__device__ __forceinline__ int pass_of(int r) { return (r < 6) ? 0 : ((r < 12) ? 1 : 2); }

__global__ void k_convX(const float* __restrict__ h, unsigned short* __restrict__ x1) {
    int i = blockIdx.x * blockDim.x + threadIdx.x;      // over N_PAD*DIM
    int v = i >> 7;
    x1[i] = (v < N_NODES) ? f2bf(h[i]) : (unsigned short)0;
}

// Wb[l][r][n][k] = bf16(W_l[r][k][n]); r==16 -> Ws_l
__global__ void k_convW(const float* __restrict__ W1, const float* __restrict__ Ws1,
                        const float* __restrict__ W2, const float* __restrict__ Ws2,
                        unsigned short* __restrict__ Wb) {
    int id = blockIdx.x * blockDim.x + threadIdx.x;     // 2*17*16384
    int l = id / 278528, rem = id % 278528;
    int r = rem >> 14, rr = rem & 16383;
    int n = rr >> 7, k = rr & 127;
    const float* W  = l ? W2 : W1;
    const float* Ws = l ? Ws2 : Ws1;
    float v = (r < 16) ? W[r * 16384 + k * 128 + n] : Ws[k * 128 + n];
    Wb[id] = f2bf(v);
}

__global__ void k_histK(const int* __restrict__ dst, const int* __restrict__ rel,
                        int* __restrict__ hist) {
    int e = blockIdx.x * blockDim.x + threadIdx.x;
    if (e < N_EDGES) atomicAdd(&hist[pass_of(rel[e]) * N_PAD + dst[e]], 1);
}

__global__ void k_scanA(const int* __restrict__ hist, int* __restrict__ partials) {
    __shared__ int red[256];
    int b = blockIdx.x, t = threadIdx.x;
    int4 v = ((const int4*)(hist + b * 1024))[t];
    red[t] = v.x + v.y + v.z + v.w;
    __syncthreads();
    for (int o = 128; o > 0; o >>= 1) {
        if (t < o) red[t] += red[t + o];
        __syncthreads();
    }
    if (t == 0) partials[b] = red[0];
}

__global__ void k_scanB(int* __restrict__ partials, int* __restrict__ offs_tail) {
    __shared__ int s1[256], s2[256];
    int t = threadIdx.x;
    int v[4]; int sum = 0;
    #pragma unroll
    for (int i = 0; i < 4; ++i) {
        int j = t * 4 + i;
        v[i] = (j < NBLK_SCAN) ? partials[j] : 0;
        sum += v[i];
    }
    s1[t] = sum; __syncthreads();
    int* cur = s1; int* nxt = s2;
    for (int o = 1; o < 256; o <<= 1) {
        nxt[t] = cur[t] + ((t >= o) ? cur[t - o] : 0);
        __syncthreads();
        int* tmp = cur; cur = nxt; nxt = tmp;
    }
    int run = cur[t] - sum;
    #pragma unroll
    for (int i = 0; i < 4; ++i) {
        int j = t * 4 + i;
        if (j < NBLK_SCAN) partials[j] = run;
        run += v[i];
    }
    if (t == 255) offs_tail[0] = cur[255];
}

__global__ void k_scanC(const int* __restrict__ hist, const int* __restrict__ partials,
                        int* __restrict__ offs, int* __restrict__ curp) {
    __shared__ int s1[256], s2[256];
    int b = blockIdx.x, t = threadIdx.x;
    int4 v = ((const int4*)(hist + b * 1024))[t];
    int sum = v.x + v.y + v.z + v.w;
    s1[t] = sum; __syncthreads();
    int* cur = s1; int* nxt = s2;
    for (int o = 1; o < 256; o <<= 1) {
        nxt[t] = cur[t] + ((t >= o) ? cur[t - o] : 0);
        __syncthreads();
        int* tmp = cur; cur = nxt; nxt = tmp;
    }
    int base = partials[b] + cur[t] - sum;
    int4 w;
    w.x = base;
    w.y = base + v.x;
    w.z = w.y + v.y;
    w.w = w.z + v.z;
    ((int4*)(offs + b * 1024))[t] = w;
    ((int4*)(curp + b * 1024))[t] = w;
}

__global__ void k_scatterK(const int* __restrict__ src, const int* __restrict__ dst,
                           const int* __restrict__ rel, int* __restrict__ cur,
                           unsigned int* __restrict__ srcs) {
    int e = blockIdx.x * blockDim.x + threadIdx.x;
    if (e < N_EDGES) {
        int r = rel[e];
        int pos = atomicAdd(&cur[pass_of(r) * N_PAD + dst[e]], 1);
        srcs[pos] = ((unsigned int)r << 16) | (unsigned int)src[e];
    }
}

// ---- Phase A: block stages 64-row X tile once, loops rels of this pass ----
__global__ __launch_bounds__(256) void k_phaseA(
    const unsigned short* __restrict__ x, const unsigned short* __restrict__ Wb,
    unsigned short* __restrict__ T, int r0, int cnt)
{
    __shared__ unsigned short Xs[64 * 136];              // 17408 B

    int tid = threadIdx.x;
    int v0 = blockIdx.x * 64;
    int w = tid >> 6, l = tid & 63;
    int nl = l & 15, q = l >> 4;

    {   // stage X tile: 4 threads/row, 4 uint4 each
        int row = tid >> 2, c0 = tid & 3;
        const uint4* xp = (const uint4*)(x + (v0 + row) * 128);
        uint4* lp = (uint4*)(&Xs[row * 136]);
        #pragma unroll
        for (int i = 0; i < 4; ++i) lp[c0 + 4 * i] = xp[c0 + 4 * i];
    }
    __syncthreads();

    for (int j = 0; j < cnt; ++j) {
        int rel = r0 + j;
        bf16x8 Bf[2][4];
        const unsigned short* wr = Wb + rel * 16384;
        #pragma unroll
        for (int nt = 0; nt < 2; ++nt) {
            int n = w * 32 + nt * 16 + nl;
            #pragma unroll
            for (int kc = 0; kc < 4; ++kc)
                Bf[nt][kc] = *(const bf16x8*)(wr + n * 128 + kc * 32 + q * 8);
        }
        unsigned short* Tb = T + (size_t)j * SLOT_ELEM + (size_t)v0 * DIM;
        #pragma unroll
        for (int m = 0; m < 4; ++m) {
            f32x4 a0 = {0.f,0.f,0.f,0.f}, a1 = {0.f,0.f,0.f,0.f};
            #pragma unroll
            for (int kc = 0; kc < 4; ++kc) {
                bf16x8 a = *(const bf16x8*)(&Xs[(m * 16 + nl) * 136 + kc * 32 + q * 8]);
                a0 = __builtin_amdgcn_mfma_f32_16x16x32_bf16(a, Bf[0][kc], a0, 0, 0, 0);
                a1 = __builtin_amdgcn_mfma_f32_16x16x32_bf16(a, Bf[1][kc], a1, 0, 0, 0);
            }
            int col = w * 32 + nl;                       // C: col=lane&15, row=q*4+reg
            #pragma unroll
            for (int reg = 0; reg < 4; ++reg) {
                int node = m * 16 + q * 4 + reg;
                Tb[node * DIM + col]      = f2bf(a0[reg]);
                Tb[node * DIM + col + 16] = f2bf(a1[reg]);
            }
        }
    }
}

// ---- Phase B: 32 dsts/block, 8 lanes/dst; pass-local contiguous edge segment ----
__global__ __launch_bounds__(256) void k_phaseB(
    const unsigned short* __restrict__ T, const unsigned int* __restrict__ srcs,
    const int* __restrict__ offs, unsigned short* __restrict__ agg,
    const float* __restrict__ bias, int r0, int pass,
    unsigned short* __restrict__ out_relu)
{
    __shared__ int sOffs[33];
    __shared__ float sBias[128];
    int tid = threadIdx.x;
    int v0 = blockIdx.x * 32;
    if (tid < 33) sOffs[tid] = offs[pass * N_PAD + v0 + tid];
    if (tid >= 64 && tid < 96) ((float4*)sBias)[tid - 64] = ((const float4*)bias)[tid - 64];
    __syncthreads();

    int g = tid >> 3, s = tid & 7;
    int dst = v0 + g;
    float qa[16];
    if (pass == 0) {
        #pragma unroll
        for (int i = 0; i < 16; ++i) qa[i] = sBias[s * 16 + i];
    } else {
        const uint4* ap = (const uint4*)(agg + dst * DIM + s * 16);
        #pragma unroll
        for (int i = 0; i < 16; ++i) qa[i] = 0.f;
        uint4 u0 = ap[0], u1 = ap[1];
        accum8(qa, u0); accum8(qa + 8, u1);
    }

    int beg = sOffs[g], end = sOffs[g + 1];
    int e = beg;
    for (; e + 1 < end; e += 2) {                        // 2-way unroll for MLP
        unsigned int rec0 = srcs[e], rec1 = srcs[e + 1];
        const uint4* tp0 = (const uint4*)(T + ((size_t)((rec0 >> 16) - r0) * SLOT_ELEM
                                               + (rec0 & 0xffffu) * DIM) + s * 16);
        const uint4* tp1 = (const uint4*)(T + ((size_t)((rec1 >> 16) - r0) * SLOT_ELEM
                                               + (rec1 & 0xffffu) * DIM) + s * 16);
        uint4 a0 = tp0[0], a1 = tp0[1], b0 = tp1[0], b1 = tp1[1];
        accum8(qa, a0); accum8(qa + 8, a1);
        accum8(qa, b0); accum8(qa + 8, b1);
    }
    if (e < end) {
        unsigned int rec = srcs[e];
        const uint4* tp = (const uint4*)(T + ((size_t)((rec >> 16) - r0) * SLOT_ELEM
                                              + (rec & 0xffffu) * DIM) + s * 16);
        uint4 u0 = tp[0], u1 = tp[1];
        accum8(qa, u0); accum8(qa + 8, u1);
    }
    if (pass == 2) {                                     // self-loop: T slot 16-r0
        const uint4* tp = (const uint4*)(T + ((size_t)(16 - r0) * SLOT_ELEM
                                              + (size_t)dst * DIM) + s * 16);
        uint4 u0 = tp[0], u1 = tp[1];
        accum8(qa, u0); accum8(qa + 8, u1);
    }

    if (out_relu) {                                      // pass 2, layer 0: relu -> x2
        float qr[16];
        #pragma unroll
        for (int i = 0; i < 16; ++i) qr[i] = fmaxf(qa[i], 0.f);
        pack16(qr, out_relu + dst * DIM + s * 16);
    } else {
        pack16(qa, agg + dst * DIM + s * 16);
    }
}

__global__ void k_pool(const unsigned short* __restrict__ agg2, const int* __restrict__ gids,
                       float* __restrict__ hg_sum, int* __restrict__ cnt)
{
    int d  = threadIdx.x;                    // 128
    int n0 = blockIdx.x * POOL_CH;
    int nend = min(n0 + POOL_CH, N_NODES);
    int curg = gids[n0];
    float run = 0.f;
    for (int n = n0; n < nend; ++n) {
        int g = gids[n];
        if (g != curg) { atomAddF(&hg_sum[curg*DIM + d], run); run = 0.f; curg = g; }
        run += fmaxf(bf2f((unsigned int)agg2[n*DIM + d]), 0.f);
    }
    atomAddF(&hg_sum[curg*DIM + d], run);
    if (d == 0) {
        int cg = gids[n0]; int rl = 0;
        for (int n = n0; n < nend; ++n) {
            int g = gids[n];
            if (g != cg) { atomicAdd(&cnt[cg], rl); rl = 0; cg = g; }
            rl++;
        }
        atomicAdd(&cnt[cg], rl);
    }
}

__global__ __launch_bounds__(256) void k_head(
    const float* __restrict__ hg_sum, const int* __restrict__ cnt,
    const float* __restrict__ Wfc, const float* __restrict__ bfc,
    const float* __restrict__ Wc, const float* __restrict__ bc,
    float* __restrict__ out)
{
    int g = blockIdx.x, t = threadIdx.x;
    __shared__ float hgl[DIM];
    __shared__ float fcl[FC_DIM];
    __shared__ float lg[N_CLASSES];
    if (t < DIM) {
        float c = (float)max(cnt[g], 1);
        hgl[t] = hg_sum[g*DIM + t] / c;
    }
    __syncthreads();
    {
        float sv = bfc[t];
        #pragma unroll 4
        for (int k = 0; k < DIM; ++k) sv += hgl[k] * Wfc[k*FC_DIM + t];
        fcl[t] = fmaxf(sv, 0.f);
    }
    __syncthreads();
    if (t < N_CLASSES) {
        float lgt = bc[t];
        #pragma unroll 4
        for (int k = 0; k < FC_DIM; ++k) lgt += fcl[k] * Wc[k*N_CLASSES + t];
        lg[t] = lgt;
    }
    __syncthreads();
    if (t < N_CLASSES) {
        float m = lg[0];
        #pragma unroll
        for (int c = 1; c < N_CLASSES; ++c) m = fmaxf(m, lg[c]);
        float sden = 0.f;
        #pragma unroll
        for (int c = 0; c < N_CLASSES; ++c) sden += expf(lg[c] - m);
        out[g*N_CLASSES + t] = expf(lg[t] - m) / sden;
    }
}

extern "C" void kernel_launch(void* const* d_in, const int* in_sizes, int n_in,
                              void* d_out, int out_size, void* d_ws, size_t ws_size,
                              hipStream_t stream)
{
    const float* h   = (const float*)d_in[0];
    const int*   src = (const int*)d_in[1];
    const int*   dst = (const int*)d_in[2];
    const int*   rel = (const int*)d_in[3];
    const int*   gid = (const int*)d_in[4];
    const float* W1  = (const float*)d_in[5];
    const float* Ws1 = (const float*)d_in[6];
    const float* b1  = (const float*)d_in[7];
    const float* W2  = (const float*)d_in[8];
    const float* Ws2 = (const float*)d_in[9];
    const float* b2  = (const float*)d_in[10];
    const float* Wfc = (const float*)d_in[11];
    const float* bfc = (const float*)d_in[12];
    const float* Wc  = (const float*)d_in[13];
    const float* bc  = (const float*)d_in[14];
    float* out = (float*)d_out;

    char* ws = (char*)d_ws;
    int*   hist  = (int*)(ws + WS_HIST);
    float* hgsum = (float*)(ws + WS_HG);
    int*   cnt   = (int*)(ws + WS_CNT);
    int*   offs  = (int*)(ws + WS_OFFS);
    int*   cur   = (int*)(ws + WS_CUR);
    int*   part  = (int*)(ws + WS_PART);
    unsigned int* srcs = (unsigned int*)(ws + WS_SRCS);
    unsigned short* x1  = (unsigned short*)(ws + WS_X1);
    unsigned short* x2  = (unsigned short*)(ws + WS_X2);
    unsigned short* agg = (unsigned short*)(ws + WS_AGG);
    unsigned short* Wb  = (unsigned short*)(ws + WS_WB);
    unsigned short* T   = (unsigned short*)(ws + WS_T);   // 6 slots, reused per pass

    hipMemsetAsync(hist, 0, MEMSET_SZ, stream);

    k_convX<<<(N_PAD * DIM) / 256, 256, 0, stream>>>(h, x1);
    k_convW<<<(2 * 17 * 16384) / 256, 256, 0, stream>>>(W1, Ws1, W2, Ws2, Wb);

    k_histK<<<(N_EDGES + 255) / 256, 256, 0, stream>>>(dst, rel, hist);
    k_scanA<<<NBLK_SCAN, 256, 0, stream>>>(hist, part);
    k_scanB<<<1, 256, 0, stream>>>(part, offs + NBINS_P);
    k_scanC<<<NBLK_SCAN, 256, 0, stream>>>(hist, part, offs, cur);
    k_scatterK<<<(N_EDGES + 255) / 256, 256, 0, stream>>>(src, dst, rel, cur, srcs);

    static const int R0[NPASS]  = {0, 6, 12};
    static const int CNTP[NPASS] = {6, 6, 5};
    for (int layer = 0; layer < 2; ++layer) {
        const unsigned short* xin = layer ? x2 : x1;
        const unsigned short* WbL = Wb + layer * 17 * 16384;
        const float* bL = layer ? b2 : b1;
        for (int p = 0; p < NPASS; ++p) {
            k_phaseA<<<NBLK_B, 256, 0, stream>>>(xin, WbL, T, R0[p], CNTP[p]);
            k_phaseB<<<N_PAD / 32, 256, 0, stream>>>(T, srcs, offs, agg, bL, R0[p], p,
                                                     (layer == 0 && p == 2) ? x2 : nullptr);
        }
    }

    k_pool<<<NBLK_B, 128, 0, stream>>>(agg, gid, hgsum, cnt);
    k_head<<<N_GRAPHS, 256, 0, stream>>>(hgsum, cnt, Wfc, bfc, Wc, bc, out);
}